// Round 20
// baseline (627.213 us; speedup 1.0000x reference)
//
#include <hip/hip_runtime.h>

typedef __attribute__((ext_vector_type(4))) float fx4;
typedef __attribute__((ext_vector_type(8))) unsigned short u16x8;
typedef __attribute__((ext_vector_type(8))) __bf16 bf16x8;

// Native bf16 cast (RTNE): hipcc lowers adjacent pairs to v_cvt_pk_bf16_f32.
static __device__ __forceinline__ unsigned short f2bf(float f) {
  return __builtin_bit_cast(unsigned short, (__bf16)f);
}
static __device__ __forceinline__ fx4 mfma16(u16x8 a, u16x8 b, fx4 c) {
  return __builtin_amdgcn_mfma_f32_16x16x32_bf16(
      __builtin_bit_cast(bf16x8, a), __builtin_bit_cast(bf16x8, b), c, 0, 0, 0);
}

// XOR swizzles (16B-block granular). Weights are PRE-swizzled in ws by prep,
// so kernels copy them linearly into LDS and read with the same swizzle.
static __device__ __forceinline__ int swz128(int row, int col) {  // [.][128] bf16
  return row * 128 + (col ^ ((row & 7) << 3));
}
static __device__ __forceinline__ int swz32(int row, int col) {   // [.][32] bf16
  return row * 32 + (col ^ (((row >> 1) & 3) << 3));
}

// ---- ws layout (ushort units): weights bf16, [N][Kpad], pre-swizzled ----
#define WT_FE1 0        // [128][32]  (fe_W1, K=18 pad 32)
#define WT_FE2 4096     // [128][128] (fe_W2)
#define WT_EE1 20480    // [128][32]  (ee_W1, K=4 pad 32)
#define WT_EE2 24576    // [128][128] (ee_W2)
#define WT_A   40960    // [128][128] (ie_W1 rows 0..127   : sr_sum)
#define WT_B   57344    // [128][128] (ie_W1 rows 128..255 : node_sum)
#define WT_C   73728    // [128][128] (ie_W1 rows 256..383 : edge_latent)
#define WT_IE2 90112    // [128][128] (ie_W2)
#define WT_TOTAL 106496

__global__ void prep_weights(const float* __restrict__ feW1, const float* __restrict__ feW2,
                             const float* __restrict__ eeW1, const float* __restrict__ eeW2,
                             const float* __restrict__ ieW1, const float* __restrict__ ieW2,
                             unsigned short* __restrict__ wt) {
  int i = blockIdx.x * 256 + threadIdx.x;
  if (i >= WT_TOTAL) return;
  int base, n, k, kpad;
  float val;
  if (i < WT_FE2)      { base = WT_FE1; n = i >> 5; k = i & 31; kpad = 32;
                         val = (k < 18) ? feW1[k * 128 + n] : 0.f; }
  else if (i < WT_EE1) { base = WT_FE2; int j = i - WT_FE2; n = j >> 7; k = j & 127; kpad = 128;
                         val = feW2[k * 128 + n]; }
  else if (i < WT_EE2) { base = WT_EE1; int j = i - WT_EE1; n = j >> 5; k = j & 31; kpad = 32;
                         val = (k < 4) ? eeW1[k * 128 + n] : 0.f; }
  else if (i < WT_A)   { base = WT_EE2; int j = i - WT_EE2; n = j >> 7; k = j & 127; kpad = 128;
                         val = eeW2[k * 128 + n]; }
  else if (i < WT_B)   { base = WT_A;   int j = i - WT_A;   n = j >> 7; k = j & 127; kpad = 128;
                         val = ieW1[k * 128 + n]; }
  else if (i < WT_C)   { base = WT_B;   int j = i - WT_B;   n = j >> 7; k = j & 127; kpad = 128;
                         val = ieW1[(128 + k) * 128 + n]; }
  else if (i < WT_IE2) { base = WT_C;   int j = i - WT_C;   n = j >> 7; k = j & 127; kpad = 128;
                         val = ieW1[(256 + k) * 128 + n]; }
  else                 { base = WT_IE2; int j = i - WT_IE2; n = j >> 7; k = j & 127; kpad = 128;
                         val = ieW2[k * 128 + n]; }
  int dst = (kpad == 32) ? base + n * 32 + (k ^ (((n >> 1) & 3) << 3))
                         : base + n * 128 + (k ^ ((n & 7) << 3));
  wt[dst] = f2bf(val);
}

// 16-row GEMM, A from wave-local LDS arena, B from LDS (or global) weights,
// both swizzled.
template<int KPAD, int KT>
static __device__ __forceinline__ void gemm_lds(const unsigned short* As,
                                                const unsigned short* Ws,
                                                fx4* acc, int l16, int lgr) {
#pragma unroll
  for (int kk = 0; kk < KT; kk++) {
    const int k0 = kk * 32 + lgr * 8;
    u16x8 af = *(const u16x8*)(As + ((KPAD == 32) ? swz32(l16, k0) : swz128(l16, k0)));
#pragma unroll
    for (int nt = 0; nt < 8; nt++) {
      const int n = nt * 16 + l16;
      u16x8 bf = *(const u16x8*)(Ws + ((KPAD == 32) ? swz32(n, k0) : swz128(n, k0)));
      acc[nt] = mfma16(af, bf, acc[nt]);
    }
  }
}

// bias + ReLU -> bf16 store into wave-local [16][128] LDS slice.
static __device__ __forceinline__ void relu_store(fx4* acc, const float* __restrict__ bias,
                                                  unsigned short* dst, int l16, int lgr) {
#pragma unroll
  for (int nt = 0; nt < 8; nt++) {
    const int col = nt * 16 + l16;
    const float b = bias[col];
#pragma unroll
    for (int r = 0; r < 4; r++) {
      float v = acc[nt][r] + b;
      dst[swz128(lgr * 4 + r, col)] = f2bf(v > 0.f ? v : 0.f);
    }
  }
}

// bias add + per-row LayerNorm (normalize only; caller applies g/beta).
static __device__ __forceinline__ void ln_rows(fx4* acc, const float* __restrict__ bias, int l16) {
  float sum[4] = {0, 0, 0, 0}, sq[4] = {0, 0, 0, 0};
#pragma unroll
  for (int nt = 0; nt < 8; nt++) {
    const float b = bias[nt * 16 + l16];
#pragma unroll
    for (int r = 0; r < 4; r++) {
      float v = acc[nt][r] + b; acc[nt][r] = v;
      sum[r] += v; sq[r] += v * v;
    }
  }
#pragma unroll
  for (int r = 0; r < 4; r++) {
    float s_ = sum[r], q_ = sq[r];
#pragma unroll
    for (int m = 1; m < 16; m <<= 1) { s_ += __shfl_xor(s_, m, 64); q_ += __shfl_xor(q_, m, 64); }
    const float mu = s_ * (1.f / 128.f);
    const float rs = rsqrtf(q_ * (1.f / 128.f) - mu * mu + 1e-5f);
#pragma unroll
    for (int nt = 0; nt < 8; nt++) acc[nt][r] = (acc[nt][r] - mu) * rs;
  }
}

// ======================= fused fe+ee kernel (256 threads) =======================
// fe LDS: W1 8KB + W2 32KB + 4 x 8KB arenas (feat ALIASED onto h1, disjoint
// lifetimes) = 72KB -> 2 blocks/CU (<=72KB is the measured co-residency
// threshold, R16/R17). Zero-cols rewritten per tile.
struct ParamsFE {
  const float* basis[3];
  const float* sv[6]; const float* rv[6];
  const float* b1; const float* b2; const float* g; const float* be;
};
struct ParamsEE {
  const float* dx; const float* attr;
  const float* b1; const float* b2; const float* g; const float* be;
};

static __device__ __forceinline__ void fe_body(const ParamsFE& p, unsigned short* lds,
                                               const unsigned short* wt, unsigned short* msg,
                                               int bid, int nblocks, int ntiles) {
  const int tid = threadIdx.x;
  const int wave = tid >> 6, lane = tid & 63;
  const int l16 = lane & 15, lgr = lane >> 4;
#pragma unroll
  for (int i = tid * 8; i < 20480; i += 2048)
    *(u16x8*)(lds + i) = *(const u16x8*)(wt + WT_FE1 + i);
  const unsigned short* W1 = lds;
  const unsigned short* W2 = lds + 4096;
  unsigned short* h1 = lds + 20480 + wave * 4096;    // [32][128]
  unsigned short* feat = h1;                         // ALIAS: [32][32], disjoint lifetime
  __syncthreads();
  const fx4 z4 = {0.f, 0.f, 0.f, 0.f};

  for (int t = bid; t < ntiles; t += nblocks) {
    const int e0 = t * 64 + wave * 16;
    const size_t e = (size_t)(e0 + l16);
    // zero cols 18..31 (rewritten every tile: relu_store clobbers the alias)
#pragma unroll
    for (int j = 0; j < 4; j++) {
      int c = 18 + lgr * 4 + j;
      if (c < 32) { feat[swz32(l16, c)] = 0; feat[swz32(16 + l16, c)] = 0; }
    }
    float bx[3][3];
#pragma unroll
    for (int i = 0; i < 3; i++) {
      const float* bp = p.basis[i] + 3 * e;
      bx[i][0] = bp[0]; bx[i][1] = bp[1]; bx[i][2] = bp[2];
    }
    // features: rows l16 = sender, 16+l16 = receiver (compile-time k, rule #20)
#pragma unroll
    for (int k = 0; k < 6; k++) {
      if ((k & 3) == lgr) {
        const float* vs = p.sv[k] + 3 * e;
        const float* vr = p.rv[k] + 3 * e;
        const float s0 = vs[0], s1 = vs[1], s2 = vs[2];
        const float r0 = vr[0], r1 = vr[1], r2 = vr[2];
        const float sgn = (k != 3 && k != 5) ? -1.f : 1.f;  // receiver signs
#pragma unroll
        for (int i = 0; i < 3; i++) {
          feat[swz32(l16, k * 3 + i)] =
              f2bf(bx[i][0] * s0 + bx[i][1] * s1 + bx[i][2] * s2);
          feat[swz32(16 + l16, k * 3 + i)] =
              f2bf((bx[i][0] * r0 + bx[i][1] * r1 + bx[i][2] * r2) * sgn);
        }
      }
    }
    fx4 accA[8], accB[8];
#pragma unroll
    for (int b = 0; b < 8; b++) { accA[b] = z4; accB[b] = z4; }
    // layer1 K=32, B (W1, LDS) shared by both halves; feat reads complete
    // before relu_store overwrites the aliased region (per-wave program order)
    {
      const int k0 = lgr * 8;
      u16x8 afA = *(const u16x8*)(feat + swz32(l16, k0));
      u16x8 afB = *(const u16x8*)(feat + swz32(16 + l16, k0));
#pragma unroll
      for (int nt = 0; nt < 8; nt++) {
        u16x8 bf = *(const u16x8*)(W1 + swz32(nt * 16 + l16, k0));
        accA[nt] = mfma16(afA, bf, accA[nt]);
        accB[nt] = mfma16(afB, bf, accB[nt]);
      }
    }
    relu_store(accA, p.b1, h1, l16, lgr);
    relu_store(accB, p.b1, h1 + 2048, l16, lgr);
#pragma unroll
    for (int b = 0; b < 8; b++) { accA[b] = z4; accB[b] = z4; }
    // layer2 K=128, B (W2, LDS) shared
#pragma unroll
    for (int c = 0; c < 4; c++) {
      const int k0 = c * 32 + lgr * 8;
      u16x8 afA = *(const u16x8*)(h1 + swz128(l16, k0));
      u16x8 afB = *(const u16x8*)(h1 + 2048 + swz128(l16, k0));
#pragma unroll
      for (int nt = 0; nt < 8; nt++) {
        u16x8 bf = *(const u16x8*)(W2 + swz128(nt * 16 + l16, k0));
        accA[nt] = mfma16(afA, bf, accA[nt]);
        accB[nt] = mfma16(afB, bf, accB[nt]);
      }
    }
    ln_rows(accA, p.b2, l16);
    ln_rows(accB, p.b2, l16);
    // sr_sum = (lnA*g+be) + (lnB*g+be), straight to msg cols 0..127
#pragma unroll
    for (int nt = 0; nt < 8; nt++) {
      const int col = nt * 16 + l16;
      const float gg = p.g[col], bb = p.be[col];
#pragma unroll
      for (int r = 0; r < 4; r++)
        msg[(size_t)(e0 + lgr * 4 + r) * 256 + col] =
            f2bf(accA[nt][r] * gg + bb + accB[nt][r] * gg + bb);
    }
  }
}

static __device__ __forceinline__ void ee_body(const ParamsEE& p, unsigned short* lds,
                                               const unsigned short* wt, unsigned short* msg,
                                               int bid, int nblocks, int ntiles) {
  const int tid = threadIdx.x;
  const int wave = tid >> 6, lane = tid & 63;
  const int l16 = lane & 15, lgr = lane >> 4;
#pragma unroll
  for (int i = tid * 8; i < 20480; i += 2048)
    *(u16x8*)(lds + i) = *(const u16x8*)(wt + WT_EE1 + i);
  const unsigned short* W1 = lds;
  const unsigned short* W2 = lds + 4096;
  unsigned short* h1 = lds + 20480 + wave * 2048;    // [16][128]
  unsigned short* feat = h1;                         // ALIAS: [16][32]
  __syncthreads();
  const fx4 z4 = {0.f, 0.f, 0.f, 0.f};

  for (int t = bid; t < ntiles; t += nblocks) {
    const int e0 = t * 64 + wave * 16;
    const size_t e = (size_t)(e0 + l16);
    // zeros cols 4..31 rewritten each tile (alias clobbered by relu_store)
#pragma unroll
    for (int j = 0; j < 7; j++) feat[swz32(l16, 4 + lgr * 7 + j)] = 0;
    if (lgr == 0) {
      float d0 = p.dx[3 * e], d1 = p.dx[3 * e + 1], d2 = p.dx[3 * e + 2];
      feat[swz32(l16, 0)] = f2bf(sqrtf(d0 * d0 + d1 * d1 + d2 * d2));
    } else {
      feat[swz32(l16, lgr)] = f2bf(p.attr[3 * e + (lgr - 1)]);
    }
    fx4 acc[8];
#pragma unroll
    for (int b = 0; b < 8; b++) acc[b] = z4;
    gemm_lds<32, 1>(feat, W1, acc, l16, lgr);
    relu_store(acc, p.b1, h1, l16, lgr);
#pragma unroll
    for (int b = 0; b < 8; b++) acc[b] = z4;
    gemm_lds<128, 4>(h1, W2, acc, l16, lgr);
    ln_rows(acc, p.b2, l16);
#pragma unroll
    for (int nt = 0; nt < 8; nt++) {
      const int col = nt * 16 + l16;
      const float gg = p.g[col], bb = p.be[col];
#pragma unroll
      for (int r = 0; r < 4; r++)
        msg[(size_t)(e0 + lgr * 4 + r) * 256 + 128 + col] =
            f2bf(acc[nt][r] * gg + bb);
    }
  }
}

__global__ __launch_bounds__(256) void feee_kernel(ParamsFE pf, ParamsEE pe,
                                                   const unsigned short* wt,
                                                   unsigned short* msg,
                                                   int nfe, int ntiles) {
  extern __shared__ unsigned short lds[];  // 36864 ushorts (72KB) -> 2 blk/CU
  if ((int)blockIdx.x < nfe)
    fe_body(pf, lds, wt, msg, blockIdx.x, nfe, ntiles);
  else
    ee_body(pe, lds, wt, msg, blockIdx.x - nfe, gridDim.x - nfe, ntiles);
}

// ============ ie kernel (fused layer1 + layer2 + LN -> out f32) ============
// R15 resources: 512 thr, WA|WB|WC 96KB LDS + 8 x 4KB arenas, 1 blk/CU,
// W2 from GLOBAL (one 32KB L1-resident table; R12: >=2 thrash).
// R20: node-gather chunks 0-1 for tile t+1 are issued AFTER LN but BEFORE the
// out-stores: (a) HBM-latency gathers (~600-900cy, random 512B rows of the
// 32MB node table) get a full extra phase of cover; (b) vmcnt is oldest-first,
// so ordering gathers AHEAD of the 32 stores means their wait no longer
// drains the store queue. Chunks 2-3 stay at loop-top. Peak live ~110 < 128.
struct ParamsIE {
  const int* eidx;
  const float* nl;
  const float* b1; const float* b2; const float* g; const float* be;
  const unsigned short* wt;
  const unsigned short* msg;  // aliases out (rows consumed before overwrite)
  float* out;
  int E; int ntiles;
};

__global__ __launch_bounds__(512) void ie_kernel(ParamsIE p) {
  extern __shared__ unsigned short dyn[];  // 49152 weights + 8*2048 arenas
  const int tid = threadIdx.x;
  const int wave = tid >> 6, lane = tid & 63;
  const int l16 = lane & 15, lgr = lane >> 4;
#pragma unroll
  for (int i = tid * 8; i < 49152; i += 4096)
    *(u16x8*)(dyn + i) = *(const u16x8*)(p.wt + WT_A + i);
  const unsigned short* WA = dyn;
  const unsigned short* WB = dyn + 16384;
  const unsigned short* WC = dyn + 32768;
  unsigned short* h1 = dyn + 49152 + wave * 2048;
  __syncthreads();
  const fx4 z4 = {0.f, 0.f, 0.f, 0.f};
  const int gstride = gridDim.x;

  int t = blockIdx.x;
  int sidx = 0, ridx = 0;
  u16x8 xs[4], xe[4];
  fx4 na[2][2], nb[2][2];   // node-gather chunks 0..1, issued one phase early
  if (t < p.ntiles) {       // prologue prefetch for the first tile
    const size_t e = (size_t)(t * 128 + wave * 16 + l16);
    sidx = p.eidx[e];
    ridx = p.eidx[(size_t)p.E + e];
    const unsigned short* mrow = p.msg + e * 256;
#pragma unroll
    for (int c = 0; c < 4; c++) {
      const int k0 = c * 32 + lgr * 8;
      xs[c] = *(const u16x8*)(mrow + k0);
      xe[c] = *(const u16x8*)(mrow + 128 + k0);
    }
    const float* ns0 = p.nl + (size_t)sidx * 128;
    const float* nr0 = p.nl + (size_t)ridx * 128;
#pragma unroll
    for (int c = 0; c < 2; c++) {
      const int k0 = c * 32 + lgr * 8;
      na[c][0] = *(const fx4*)(ns0 + k0); na[c][1] = *(const fx4*)(ns0 + k0 + 4);
      nb[c][0] = *(const fx4*)(nr0 + k0); nb[c][1] = *(const fx4*)(nr0 + k0 + 4);
    }
  }

  for (; t < p.ntiles; t += gstride) {
    const int e0 = t * 128 + wave * 16;
    const float* ns = p.nl + (size_t)sidx * 128;   // current tile's nodes
    const float* nr = p.nl + (size_t)ridx * 128;
    // ---- issue node-gather loads for chunks 2..3 (fly under sr/el phases) ----
    fx4 nc[2][2], nd[2][2];
#pragma unroll
    for (int c = 0; c < 2; c++) {
      const int k0 = (c + 2) * 32 + lgr * 8;
      nc[c][0] = *(const fx4*)(ns + k0); nc[c][1] = *(const fx4*)(ns + k0 + 4);
      nd[c][0] = *(const fx4*)(nr + k0); nd[c][1] = *(const fx4*)(nr + k0 + 4);
    }
    fx4 acc[8];
#pragma unroll
    for (int b = 0; b < 8; b++) acc[b] = z4;
    // ---- sr phase (LDS-only: xs + WA) ----
#pragma unroll
    for (int c = 0; c < 4; c++) {
      const int k0 = c * 32 + lgr * 8;
#pragma unroll
      for (int nt = 0; nt < 8; nt++) {
        u16x8 bf = *(const u16x8*)(WA + swz128(nt * 16 + l16, k0));
        acc[nt] = mfma16(xs[c], bf, acc[nt]);
      }
    }
    // ---- el phase (LDS-only: xe + WC) ----
#pragma unroll
    for (int c = 0; c < 4; c++) {
      const int k0 = c * 32 + lgr * 8;
#pragma unroll
      for (int nt = 0; nt < 8; nt++) {
        u16x8 bf = *(const u16x8*)(WC + swz128(nt * 16 + l16, k0));
        acc[nt] = mfma16(xe[c], bf, acc[nt]);
      }
    }
    // ---- node phase (na/nb issued LAST tile, nc/nd at loop-top) ----
#pragma unroll
    for (int c = 0; c < 4; c++) {
      const int k0 = c * 32 + lgr * 8;
      fx4 s0 = (c < 2) ? na[c & 1][0] : nc[c & 1][0];
      fx4 s1 = (c < 2) ? na[c & 1][1] : nc[c & 1][1];
      fx4 r0 = (c < 2) ? nb[c & 1][0] : nd[c & 1][0];
      fx4 r1 = (c < 2) ? nb[c & 1][1] : nd[c & 1][1];
      u16x8 af;
#pragma unroll
      for (int j = 0; j < 4; j++) { af[j] = f2bf(s0[j] + r0[j]); af[4 + j] = f2bf(s1[j] + r1[j]); }
#pragma unroll
      for (int nt = 0; nt < 8; nt++) {
        u16x8 bf = *(const u16x8*)(WB + swz128(nt * 16 + l16, k0));
        acc[nt] = mfma16(af, bf, acc[nt]);
      }
    }
    // ReLU -> per-wave LDS arena
    relu_store(acc, p.b1, h1, l16, lgr);
    // ---- prefetch NEXT tile (eidx + msg fragments) before layer2 ----
    const int tn = t + gstride;
    if (tn < p.ntiles) {
      const size_t en = (size_t)(tn * 128 + wave * 16 + l16);
      sidx = p.eidx[en];
      ridx = p.eidx[(size_t)p.E + en];
      const unsigned short* mrow2 = p.msg + en * 256;
#pragma unroll
      for (int c = 0; c < 4; c++) {
        const int k0 = c * 32 + lgr * 8;
        xs[c] = *(const u16x8*)(mrow2 + k0);
        xe[c] = *(const u16x8*)(mrow2 + 128 + k0);
      }
    }
    // layer 2: A from arena (LDS), B from global W2 (L1-resident 32KB)
#pragma unroll
    for (int b = 0; b < 8; b++) acc[b] = z4;
    gemm_lds<128, 4>(h1, p.wt + WT_IE2, acc, l16, lgr);
    ln_rows(acc, p.b2, l16);
    // ---- issue NEXT tile's node-gather chunks 0..1 BEFORE the stores ----
    if (tn < p.ntiles) {
      const float* ns2 = p.nl + (size_t)sidx * 128;   // sidx/ridx = next tile
      const float* nr2 = p.nl + (size_t)ridx * 128;
#pragma unroll
      for (int c = 0; c < 2; c++) {
        const int k0 = c * 32 + lgr * 8;
        na[c][0] = *(const fx4*)(ns2 + k0); na[c][1] = *(const fx4*)(ns2 + k0 + 4);
        nb[c][0] = *(const fx4*)(nr2 + k0); nb[c][1] = *(const fx4*)(nr2 + k0 + 4);
      }
    }
#pragma unroll
    for (int nt = 0; nt < 8; nt++) {
      const int col = nt * 16 + l16;
      const float gg = p.g[col], bb = p.be[col];
#pragma unroll
      for (int r = 0; r < 4; r++)
        p.out[(size_t)(e0 + lgr * 4 + r) * 128 + col] = acc[nt][r] * gg + bb;
    }
  }
}

extern "C" void kernel_launch(void* const* d_in, const int* in_sizes, int n_in,
                              void* d_out, int out_size, void* d_ws, size_t ws_size,
                              hipStream_t stream) {
  (void)n_in; (void)out_size;
  const int E = in_sizes[1] / 3;  // edge_dx_ is [E,3]
  unsigned short* wt = reinterpret_cast<unsigned short*>(d_ws);
  if (ws_size < (size_t)WT_TOTAL * sizeof(unsigned short)) return;

  prep_weights<<<(WT_TOTAL + 255) / 256, 256, 0, stream>>>(
      (const float*)d_in[19], (const float*)d_in[21],
      (const float*)d_in[25], (const float*)d_in[27],
      (const float*)d_in[31], (const float*)d_in[33], wt);

  unsigned short* msg = (unsigned short*)d_out;  // [E][256] bf16 staging inside d_out

  hipFuncSetAttribute((const void*)feee_kernel,
                      hipFuncAttributeMaxDynamicSharedMemorySize, 73728);
  hipFuncSetAttribute((const void*)ie_kernel,
                      hipFuncAttributeMaxDynamicSharedMemorySize, 131072);

  ParamsFE pf;
  for (int i = 0; i < 3; i++) pf.basis[i] = (const float*)d_in[3 + i];
  for (int k = 0; k < 6; k++) { pf.sv[k] = (const float*)d_in[6 + k]; pf.rv[k] = (const float*)d_in[12 + k]; }
  pf.b1 = (const float*)d_in[20]; pf.b2 = (const float*)d_in[22];
  pf.g  = (const float*)d_in[23]; pf.be = (const float*)d_in[24];

  ParamsEE pe;
  pe.dx = (const float*)d_in[1]; pe.attr = (const float*)d_in[2];
  pe.b1 = (const float*)d_in[26]; pe.b2 = (const float*)d_in[28];
  pe.g  = (const float*)d_in[29]; pe.be = (const float*)d_in[30];

  // fe: E/64 tiles over 1024 blocks; ee: E/64 tiles over 512 blocks (~2:1 work)
  feee_kernel<<<1536, 256, 73728, stream>>>(pf, pe, wt, msg, 1024, E / 64);

  ParamsIE pi;
  pi.eidx = (const int*)d_in[0];
  pi.nl = (const float*)d_in[18];
  pi.b1 = (const float*)d_in[32]; pi.b2 = (const float*)d_in[34];
  pi.g  = (const float*)d_in[35]; pi.be = (const float*)d_in[36];
  pi.wt = wt; pi.msg = msg; pi.out = (float*)d_out;
  pi.E = E; pi.ntiles = E / 128;
  ie_kernel<<<256, 512, 131072, stream>>>(pi);
}

// Round 21
// 512.861 us; speedup vs baseline: 1.2230x; 1.2230x over previous
//
#include <hip/hip_runtime.h>

typedef __attribute__((ext_vector_type(4))) float fx4;
typedef __attribute__((ext_vector_type(8))) unsigned short u16x8;
typedef __attribute__((ext_vector_type(8))) __bf16 bf16x8;

// Native bf16 cast (RTNE): hipcc lowers adjacent pairs to v_cvt_pk_bf16_f32.
static __device__ __forceinline__ unsigned short f2bf(float f) {
  return __builtin_bit_cast(unsigned short, (__bf16)f);
}
static __device__ __forceinline__ fx4 mfma16(u16x8 a, u16x8 b, fx4 c) {
  return __builtin_amdgcn_mfma_f32_16x16x32_bf16(
      __builtin_bit_cast(bf16x8, a), __builtin_bit_cast(bf16x8, b), c, 0, 0, 0);
}

// XOR swizzles (16B-block granular). Weights are PRE-swizzled in ws by prep,
// so kernels copy them linearly into LDS and read with the same swizzle.
static __device__ __forceinline__ int swz128(int row, int col) {  // [.][128] bf16
  return row * 128 + (col ^ ((row & 7) << 3));
}
static __device__ __forceinline__ int swz32(int row, int col) {   // [.][32] bf16
  return row * 32 + (col ^ (((row >> 1) & 3) << 3));
}

// ---- ws layout (ushort units): weights bf16, [N][Kpad], pre-swizzled ----
#define WT_FE1 0        // [128][32]  (fe_W1, K=18 pad 32)
#define WT_FE2 4096     // [128][128] (fe_W2)
#define WT_EE1 20480    // [128][32]  (ee_W1, K=4 pad 32)
#define WT_EE2 24576    // [128][128] (ee_W2)
#define WT_A   40960    // [128][128] (ie_W1 rows 0..127   : sr_sum)
#define WT_B   57344    // [128][128] (ie_W1 rows 128..255 : node_sum)
#define WT_C   73728    // [128][128] (ie_W1 rows 256..383 : edge_latent)
#define WT_IE2 90112    // [128][128] (ie_W2)
#define WT_TOTAL 106496

__global__ void prep_weights(const float* __restrict__ feW1, const float* __restrict__ feW2,
                             const float* __restrict__ eeW1, const float* __restrict__ eeW2,
                             const float* __restrict__ ieW1, const float* __restrict__ ieW2,
                             unsigned short* __restrict__ wt) {
  int i = blockIdx.x * 256 + threadIdx.x;
  if (i >= WT_TOTAL) return;
  int base, n, k, kpad;
  float val;
  if (i < WT_FE2)      { base = WT_FE1; n = i >> 5; k = i & 31; kpad = 32;
                         val = (k < 18) ? feW1[k * 128 + n] : 0.f; }
  else if (i < WT_EE1) { base = WT_FE2; int j = i - WT_FE2; n = j >> 7; k = j & 127; kpad = 128;
                         val = feW2[k * 128 + n]; }
  else if (i < WT_EE2) { base = WT_EE1; int j = i - WT_EE1; n = j >> 5; k = j & 31; kpad = 32;
                         val = (k < 4) ? eeW1[k * 128 + n] : 0.f; }
  else if (i < WT_A)   { base = WT_EE2; int j = i - WT_EE2; n = j >> 7; k = j & 127; kpad = 128;
                         val = eeW2[k * 128 + n]; }
  else if (i < WT_B)   { base = WT_A;   int j = i - WT_A;   n = j >> 7; k = j & 127; kpad = 128;
                         val = ieW1[k * 128 + n]; }
  else if (i < WT_C)   { base = WT_B;   int j = i - WT_B;   n = j >> 7; k = j & 127; kpad = 128;
                         val = ieW1[(128 + k) * 128 + n]; }
  else if (i < WT_IE2) { base = WT_C;   int j = i - WT_C;   n = j >> 7; k = j & 127; kpad = 128;
                         val = ieW1[(256 + k) * 128 + n]; }
  else                 { base = WT_IE2; int j = i - WT_IE2; n = j >> 7; k = j & 127; kpad = 128;
                         val = ieW2[k * 128 + n]; }
  int dst = (kpad == 32) ? base + n * 32 + (k ^ (((n >> 1) & 3) << 3))
                         : base + n * 128 + (k ^ ((n & 7) << 3));
  wt[dst] = f2bf(val);
}

// 16-row GEMM, A from wave-local LDS arena, B from LDS (or global) weights,
// both swizzled.
template<int KPAD, int KT>
static __device__ __forceinline__ void gemm_lds(const unsigned short* As,
                                                const unsigned short* Ws,
                                                fx4* acc, int l16, int lgr) {
#pragma unroll
  for (int kk = 0; kk < KT; kk++) {
    const int k0 = kk * 32 + lgr * 8;
    u16x8 af = *(const u16x8*)(As + ((KPAD == 32) ? swz32(l16, k0) : swz128(l16, k0)));
#pragma unroll
    for (int nt = 0; nt < 8; nt++) {
      const int n = nt * 16 + l16;
      u16x8 bf = *(const u16x8*)(Ws + ((KPAD == 32) ? swz32(n, k0) : swz128(n, k0)));
      acc[nt] = mfma16(af, bf, acc[nt]);
    }
  }
}

// bias + ReLU -> bf16 store into wave-local [16][128] LDS slice.
static __device__ __forceinline__ void relu_store(fx4* acc, const float* __restrict__ bias,
                                                  unsigned short* dst, int l16, int lgr) {
#pragma unroll
  for (int nt = 0; nt < 8; nt++) {
    const int col = nt * 16 + l16;
    const float b = bias[col];
#pragma unroll
    for (int r = 0; r < 4; r++) {
      float v = acc[nt][r] + b;
      dst[swz128(lgr * 4 + r, col)] = f2bf(v > 0.f ? v : 0.f);
    }
  }
}

// bias add + per-row LayerNorm (normalize only; caller applies g/beta).
static __device__ __forceinline__ void ln_rows(fx4* acc, const float* __restrict__ bias, int l16) {
  float sum[4] = {0, 0, 0, 0}, sq[4] = {0, 0, 0, 0};
#pragma unroll
  for (int nt = 0; nt < 8; nt++) {
    const float b = bias[nt * 16 + l16];
#pragma unroll
    for (int r = 0; r < 4; r++) {
      float v = acc[nt][r] + b; acc[nt][r] = v;
      sum[r] += v; sq[r] += v * v;
    }
  }
#pragma unroll
  for (int r = 0; r < 4; r++) {
    float s_ = sum[r], q_ = sq[r];
#pragma unroll
    for (int m = 1; m < 16; m <<= 1) { s_ += __shfl_xor(s_, m, 64); q_ += __shfl_xor(q_, m, 64); }
    const float mu = s_ * (1.f / 128.f);
    const float rs = rsqrtf(q_ * (1.f / 128.f) - mu * mu + 1e-5f);
#pragma unroll
    for (int nt = 0; nt < 8; nt++) acc[nt][r] = (acc[nt][r] - mu) * rs;
  }
}

// ======================= fused fe+ee kernel (256 threads) =======================
// fe LDS: W1 8KB + W2 32KB + 4 x 8KB arenas (feat ALIASED onto h1, disjoint
// lifetimes) = 72KB -> 2 blocks/CU (<=72KB is the measured co-residency
// threshold, R16/R17). Zero-cols rewritten per tile.
struct ParamsFE {
  const float* basis[3];
  const float* sv[6]; const float* rv[6];
  const float* b1; const float* b2; const float* g; const float* be;
};
struct ParamsEE {
  const float* dx; const float* attr;
  const float* b1; const float* b2; const float* g; const float* be;
};

static __device__ __forceinline__ void fe_body(const ParamsFE& p, unsigned short* lds,
                                               const unsigned short* wt, unsigned short* msg,
                                               int bid, int nblocks, int ntiles) {
  const int tid = threadIdx.x;
  const int wave = tid >> 6, lane = tid & 63;
  const int l16 = lane & 15, lgr = lane >> 4;
#pragma unroll
  for (int i = tid * 8; i < 20480; i += 2048)
    *(u16x8*)(lds + i) = *(const u16x8*)(wt + WT_FE1 + i);
  const unsigned short* W1 = lds;
  const unsigned short* W2 = lds + 4096;
  unsigned short* h1 = lds + 20480 + wave * 4096;    // [32][128]
  unsigned short* feat = h1;                         // ALIAS: [32][32], disjoint lifetime
  __syncthreads();
  const fx4 z4 = {0.f, 0.f, 0.f, 0.f};

  for (int t = bid; t < ntiles; t += nblocks) {
    const int e0 = t * 64 + wave * 16;
    const size_t e = (size_t)(e0 + l16);
    // zero cols 18..31 (rewritten every tile: relu_store clobbers the alias)
#pragma unroll
    for (int j = 0; j < 4; j++) {
      int c = 18 + lgr * 4 + j;
      if (c < 32) { feat[swz32(l16, c)] = 0; feat[swz32(16 + l16, c)] = 0; }
    }
    float bx[3][3];
#pragma unroll
    for (int i = 0; i < 3; i++) {
      const float* bp = p.basis[i] + 3 * e;
      bx[i][0] = bp[0]; bx[i][1] = bp[1]; bx[i][2] = bp[2];
    }
    // features: rows l16 = sender, 16+l16 = receiver (compile-time k, rule #20)
#pragma unroll
    for (int k = 0; k < 6; k++) {
      if ((k & 3) == lgr) {
        const float* vs = p.sv[k] + 3 * e;
        const float* vr = p.rv[k] + 3 * e;
        const float s0 = vs[0], s1 = vs[1], s2 = vs[2];
        const float r0 = vr[0], r1 = vr[1], r2 = vr[2];
        const float sgn = (k != 3 && k != 5) ? -1.f : 1.f;  // receiver signs
#pragma unroll
        for (int i = 0; i < 3; i++) {
          feat[swz32(l16, k * 3 + i)] =
              f2bf(bx[i][0] * s0 + bx[i][1] * s1 + bx[i][2] * s2);
          feat[swz32(16 + l16, k * 3 + i)] =
              f2bf((bx[i][0] * r0 + bx[i][1] * r1 + bx[i][2] * r2) * sgn);
        }
      }
    }
    fx4 accA[8], accB[8];
#pragma unroll
    for (int b = 0; b < 8; b++) { accA[b] = z4; accB[b] = z4; }
    // layer1 K=32, B (W1, LDS) shared by both halves; feat reads complete
    // before relu_store overwrites the aliased region (per-wave program order)
    {
      const int k0 = lgr * 8;
      u16x8 afA = *(const u16x8*)(feat + swz32(l16, k0));
      u16x8 afB = *(const u16x8*)(feat + swz32(16 + l16, k0));
#pragma unroll
      for (int nt = 0; nt < 8; nt++) {
        u16x8 bf = *(const u16x8*)(W1 + swz32(nt * 16 + l16, k0));
        accA[nt] = mfma16(afA, bf, accA[nt]);
        accB[nt] = mfma16(afB, bf, accB[nt]);
      }
    }
    relu_store(accA, p.b1, h1, l16, lgr);
    relu_store(accB, p.b1, h1 + 2048, l16, lgr);
#pragma unroll
    for (int b = 0; b < 8; b++) { accA[b] = z4; accB[b] = z4; }
    // layer2 K=128, B (W2, LDS) shared
#pragma unroll
    for (int c = 0; c < 4; c++) {
      const int k0 = c * 32 + lgr * 8;
      u16x8 afA = *(const u16x8*)(h1 + swz128(l16, k0));
      u16x8 afB = *(const u16x8*)(h1 + 2048 + swz128(l16, k0));
#pragma unroll
      for (int nt = 0; nt < 8; nt++) {
        u16x8 bf = *(const u16x8*)(W2 + swz128(nt * 16 + l16, k0));
        accA[nt] = mfma16(afA, bf, accA[nt]);
        accB[nt] = mfma16(afB, bf, accB[nt]);
      }
    }
    ln_rows(accA, p.b2, l16);
    ln_rows(accB, p.b2, l16);
    // sr_sum = (lnA*g+be) + (lnB*g+be), straight to msg cols 0..127
#pragma unroll
    for (int nt = 0; nt < 8; nt++) {
      const int col = nt * 16 + l16;
      const float gg = p.g[col], bb = p.be[col];
#pragma unroll
      for (int r = 0; r < 4; r++)
        msg[(size_t)(e0 + lgr * 4 + r) * 256 + col] =
            f2bf(accA[nt][r] * gg + bb + accB[nt][r] * gg + bb);
    }
  }
}

static __device__ __forceinline__ void ee_body(const ParamsEE& p, unsigned short* lds,
                                               const unsigned short* wt, unsigned short* msg,
                                               int bid, int nblocks, int ntiles) {
  const int tid = threadIdx.x;
  const int wave = tid >> 6, lane = tid & 63;
  const int l16 = lane & 15, lgr = lane >> 4;
#pragma unroll
  for (int i = tid * 8; i < 20480; i += 2048)
    *(u16x8*)(lds + i) = *(const u16x8*)(wt + WT_EE1 + i);
  const unsigned short* W1 = lds;
  const unsigned short* W2 = lds + 4096;
  unsigned short* h1 = lds + 20480 + wave * 2048;    // [16][128]
  unsigned short* feat = h1;                         // ALIAS: [16][32]
  __syncthreads();
  const fx4 z4 = {0.f, 0.f, 0.f, 0.f};

  for (int t = bid; t < ntiles; t += nblocks) {
    const int e0 = t * 64 + wave * 16;
    const size_t e = (size_t)(e0 + l16);
    // zeros cols 4..31 rewritten each tile (alias clobbered by relu_store)
#pragma unroll
    for (int j = 0; j < 7; j++) feat[swz32(l16, 4 + lgr * 7 + j)] = 0;
    if (lgr == 0) {
      float d0 = p.dx[3 * e], d1 = p.dx[3 * e + 1], d2 = p.dx[3 * e + 2];
      feat[swz32(l16, 0)] = f2bf(sqrtf(d0 * d0 + d1 * d1 + d2 * d2));
    } else {
      feat[swz32(l16, lgr)] = f2bf(p.attr[3 * e + (lgr - 1)]);
    }
    fx4 acc[8];
#pragma unroll
    for (int b = 0; b < 8; b++) acc[b] = z4;
    gemm_lds<32, 1>(feat, W1, acc, l16, lgr);
    relu_store(acc, p.b1, h1, l16, lgr);
#pragma unroll
    for (int b = 0; b < 8; b++) acc[b] = z4;
    gemm_lds<128, 4>(h1, W2, acc, l16, lgr);
    ln_rows(acc, p.b2, l16);
#pragma unroll
    for (int nt = 0; nt < 8; nt++) {
      const int col = nt * 16 + l16;
      const float gg = p.g[col], bb = p.be[col];
#pragma unroll
      for (int r = 0; r < 4; r++)
        msg[(size_t)(e0 + lgr * 4 + r) * 256 + 128 + col] =
            f2bf(acc[nt][r] * gg + bb);
    }
  }
}

__global__ __launch_bounds__(256) void feee_kernel(ParamsFE pf, ParamsEE pe,
                                                   const unsigned short* wt,
                                                   unsigned short* msg,
                                                   int nfe, int ntiles) {
  extern __shared__ unsigned short lds[];  // 36864 ushorts (72KB) -> 2 blk/CU
  if ((int)blockIdx.x < nfe)
    fe_body(pf, lds, wt, msg, blockIdx.x, nfe, ntiles);
  else
    ee_body(pe, lds, wt, msg, blockIdx.x - nfe, gridDim.x - nfe, ntiles);
}

// ============ ie kernel (fused layer1 + layer2 + LN -> out f32) ============
// R15/R19 config (best, 276us): 512 thr, WA|WB|WC 96KB LDS + 8 x 4KB arenas,
// 1 blk/CU, W2 from GLOBAL (one 32KB L1-resident table; R12: >=2 thrash).
// 1-deep cross-tile pipeline: node gathers split around sr/el phases, next
// tile's eidx+msg prefetched before layer2. (2-deep pipelining spills: R20
// added +96MB FETCH via rematerialization and regressed 276->404us.)
struct ParamsIE {
  const int* eidx;
  const float* nl;
  const float* b1; const float* b2; const float* g; const float* be;
  const unsigned short* wt;
  const unsigned short* msg;  // aliases out (rows consumed before overwrite)
  float* out;
  int E; int ntiles;
};

__global__ __launch_bounds__(512) void ie_kernel(ParamsIE p) {
  extern __shared__ unsigned short dyn[];  // 49152 weights + 8*2048 arenas
  const int tid = threadIdx.x;
  const int wave = tid >> 6, lane = tid & 63;
  const int l16 = lane & 15, lgr = lane >> 4;
#pragma unroll
  for (int i = tid * 8; i < 49152; i += 4096)
    *(u16x8*)(dyn + i) = *(const u16x8*)(p.wt + WT_A + i);
  const unsigned short* WA = dyn;
  const unsigned short* WB = dyn + 16384;
  const unsigned short* WC = dyn + 32768;
  unsigned short* h1 = dyn + 49152 + wave * 2048;
  __syncthreads();
  const fx4 z4 = {0.f, 0.f, 0.f, 0.f};
  const int gstride = gridDim.x;

  int t = blockIdx.x;
  int sidx = 0, ridx = 0;
  u16x8 xs[4], xe[4];
  if (t < p.ntiles) {   // prologue prefetch for the first tile
    const size_t e = (size_t)(t * 128 + wave * 16 + l16);
    sidx = p.eidx[e];
    ridx = p.eidx[(size_t)p.E + e];
    const unsigned short* mrow = p.msg + e * 256;
#pragma unroll
    for (int c = 0; c < 4; c++) {
      const int k0 = c * 32 + lgr * 8;
      xs[c] = *(const u16x8*)(mrow + k0);
      xe[c] = *(const u16x8*)(mrow + 128 + k0);
    }
  }

  for (; t < p.ntiles; t += gstride) {
    const int e0 = t * 128 + wave * 16;
    const float* ns = p.nl + (size_t)sidx * 128;
    const float* nr = p.nl + (size_t)ridx * 128;
    // ---- issue node-gather loads for chunks 0..1 (fly under sr phase) ----
    fx4 na[2][2], nb[2][2];
#pragma unroll
    for (int c = 0; c < 2; c++) {
      const int k0 = c * 32 + lgr * 8;
      na[c][0] = *(const fx4*)(ns + k0); na[c][1] = *(const fx4*)(ns + k0 + 4);
      nb[c][0] = *(const fx4*)(nr + k0); nb[c][1] = *(const fx4*)(nr + k0 + 4);
    }
    fx4 acc[8];
#pragma unroll
    for (int b = 0; b < 8; b++) acc[b] = z4;
    // ---- sr phase (LDS-only: xs + WA) ----
#pragma unroll
    for (int c = 0; c < 4; c++) {
      const int k0 = c * 32 + lgr * 8;
#pragma unroll
      for (int nt = 0; nt < 8; nt++) {
        u16x8 bf = *(const u16x8*)(WA + swz128(nt * 16 + l16, k0));
        acc[nt] = mfma16(xs[c], bf, acc[nt]);
      }
    }
    // ---- issue node-gather loads for chunks 2..3 (fly under el phase) ----
    fx4 nc[2][2], nd[2][2];
#pragma unroll
    for (int c = 0; c < 2; c++) {
      const int k0 = (c + 2) * 32 + lgr * 8;
      nc[c][0] = *(const fx4*)(ns + k0); nc[c][1] = *(const fx4*)(ns + k0 + 4);
      nd[c][0] = *(const fx4*)(nr + k0); nd[c][1] = *(const fx4*)(nr + k0 + 4);
    }
    // ---- el phase (LDS-only: xe + WC) ----
#pragma unroll
    for (int c = 0; c < 4; c++) {
      const int k0 = c * 32 + lgr * 8;
#pragma unroll
      for (int nt = 0; nt < 8; nt++) {
        u16x8 bf = *(const u16x8*)(WC + swz128(nt * 16 + l16, k0));
        acc[nt] = mfma16(xe[c], bf, acc[nt]);
      }
    }
    // ---- node phase (loads long since issued) ----
#pragma unroll
    for (int c = 0; c < 4; c++) {
      const int k0 = c * 32 + lgr * 8;
      fx4 s0 = (c < 2) ? na[c & 1][0] : nc[c & 1][0];
      fx4 s1 = (c < 2) ? na[c & 1][1] : nc[c & 1][1];
      fx4 r0 = (c < 2) ? nb[c & 1][0] : nd[c & 1][0];
      fx4 r1 = (c < 2) ? nb[c & 1][1] : nd[c & 1][1];
      u16x8 af;
#pragma unroll
      for (int j = 0; j < 4; j++) { af[j] = f2bf(s0[j] + r0[j]); af[4 + j] = f2bf(s1[j] + r1[j]); }
#pragma unroll
      for (int nt = 0; nt < 8; nt++) {
        u16x8 bf = *(const u16x8*)(WB + swz128(nt * 16 + l16, k0));
        acc[nt] = mfma16(af, bf, acc[nt]);
      }
    }
    // ReLU -> per-wave LDS arena
    relu_store(acc, p.b1, h1, l16, lgr);
    // ---- prefetch NEXT tile (eidx + msg fragments) before layer2 ----
    const int tn = t + gstride;
    if (tn < p.ntiles) {
      const size_t en = (size_t)(tn * 128 + wave * 16 + l16);
      sidx = p.eidx[en];
      ridx = p.eidx[(size_t)p.E + en];
      const unsigned short* mrow2 = p.msg + en * 256;
#pragma unroll
      for (int c = 0; c < 4; c++) {
        const int k0 = c * 32 + lgr * 8;
        xs[c] = *(const u16x8*)(mrow2 + k0);
        xe[c] = *(const u16x8*)(mrow2 + 128 + k0);
      }
    }
    // layer 2: A from arena (LDS), B from global W2 (L1-resident 32KB)
#pragma unroll
    for (int b = 0; b < 8; b++) acc[b] = z4;
    gemm_lds<128, 4>(h1, p.wt + WT_IE2, acc, l16, lgr);
    ln_rows(acc, p.b2, l16);
#pragma unroll
    for (int nt = 0; nt < 8; nt++) {
      const int col = nt * 16 + l16;
      const float gg = p.g[col], bb = p.be[col];
#pragma unroll
      for (int r = 0; r < 4; r++)
        p.out[(size_t)(e0 + lgr * 4 + r) * 128 + col] = acc[nt][r] * gg + bb;
    }
  }
}

extern "C" void kernel_launch(void* const* d_in, const int* in_sizes, int n_in,
                              void* d_out, int out_size, void* d_ws, size_t ws_size,
                              hipStream_t stream) {
  (void)n_in; (void)out_size;
  const int E = in_sizes[1] / 3;  // edge_dx_ is [E,3]
  unsigned short* wt = reinterpret_cast<unsigned short*>(d_ws);
  if (ws_size < (size_t)WT_TOTAL * sizeof(unsigned short)) return;

  prep_weights<<<(WT_TOTAL + 255) / 256, 256, 0, stream>>>(
      (const float*)d_in[19], (const float*)d_in[21],
      (const float*)d_in[25], (const float*)d_in[27],
      (const float*)d_in[31], (const float*)d_in[33], wt);

  unsigned short* msg = (unsigned short*)d_out;  // [E][256] bf16 staging inside d_out

  hipFuncSetAttribute((const void*)feee_kernel,
                      hipFuncAttributeMaxDynamicSharedMemorySize, 73728);
  hipFuncSetAttribute((const void*)ie_kernel,
                      hipFuncAttributeMaxDynamicSharedMemorySize, 131072);

  ParamsFE pf;
  for (int i = 0; i < 3; i++) pf.basis[i] = (const float*)d_in[3 + i];
  for (int k = 0; k < 6; k++) { pf.sv[k] = (const float*)d_in[6 + k]; pf.rv[k] = (const float*)d_in[12 + k]; }
  pf.b1 = (const float*)d_in[20]; pf.b2 = (const float*)d_in[22];
  pf.g  = (const float*)d_in[23]; pf.be = (const float*)d_in[24];

  ParamsEE pe;
  pe.dx = (const float*)d_in[1]; pe.attr = (const float*)d_in[2];
  pe.b1 = (const float*)d_in[26]; pe.b2 = (const float*)d_in[28];
  pe.g  = (const float*)d_in[29]; pe.be = (const float*)d_in[30];

  // fe: E/64 tiles over 1024 blocks; ee: E/64 tiles over 512 blocks (~2:1 work)
  feee_kernel<<<1536, 256, 73728, stream>>>(pf, pe, wt, msg, 1024, E / 64);

  ParamsIE pi;
  pi.eidx = (const int*)d_in[0];
  pi.nl = (const float*)d_in[18];
  pi.b1 = (const float*)d_in[32]; pi.b2 = (const float*)d_in[34];
  pi.g  = (const float*)d_in[35]; pi.be = (const float*)d_in[36];
  pi.wt = wt; pi.msg = msg; pi.out = (float*)d_out;
  pi.E = E; pi.ntiles = E / 128;
  ie_kernel<<<256, 512, 131072, stream>>>(pi);
}